// Round 12
// baseline (257.778 us; speedup 1.0000x reference)
//
#include <hip/hip_runtime.h>
#include <math.h>

typedef unsigned int uint;
typedef unsigned short ushort;

typedef __attribute__((ext_vector_type(8))) _Float16 f16x8;
typedef __attribute__((ext_vector_type(2))) _Float16 f16x2;
typedef __attribute__((ext_vector_type(16))) float floatx16;

#define NFEAT 327680   // 256*1280 feats (f16)
#define NWA   163840   // W add-part, row-major [128][1280] (f16)
#define NWP   327680   // W diff/had part, fragment-packed (f16)
// ws: fH | wA | wP | stats f32[16] | Aoi f32[128*256]

union U4H8 { uint4 u; f16x8 h; uint w[4]; };

__device__ inline ushort f2h(float f) {
  _Float16 h = (_Float16)f;          // v_cvt_f16_f32, RNE
  union { _Float16 h; ushort s; } c; c.h = h; return c.s;
}
__device__ inline f16x2 asf16x2(uint u) {
  union { uint u; f16x2 h; } c; c.u = u; return c.h;
}
__device__ inline uint asuint(f16x2 h) {
  union { f16x2 h; uint u; } c; c.h = h; return c.u;
}

// ---------------- prep: fp32 -> fp16; W split: add row-major, diff/had packed
__global__ void prep_kernel(const float* __restrict__ feats,
                            const float* __restrict__ W,
                            ushort* __restrict__ fH,
                            ushort* __restrict__ wA,
                            ushort* __restrict__ wP,
                            float* __restrict__ stats,
                            float* __restrict__ Aoi) {
  int idx = blockIdx.x * 256 + threadIdx.x;   // 3200*256 = NFEAT+NWA+NWP
  if (blockIdx.x == 0 && threadIdx.x < 16) stats[threadIdx.x] = 0.0f;
  if (idx < 32768) Aoi[idx] = 0.0f;
  if (idx < NFEAT) {
    fH[idx] = f2h(feats[idx]);
  } else {
    const int e = idx - NFEAT;
    const int o = e / 3840;
    const int c = e - o * 3840;
    const ushort v = f2h(W[e]);
    if (c < 1280) {
      wA[o * 1280 + c] = v;
    } else {
      const int cp = c - 1280;
      const int t = cp / 1280;            // 0=diff, 1=had
      const int kk = cp - t * 1280;
      const int ks = kk >> 4;
      const int khalf = (kk >> 3) & 1;
      const int ko = kk & 7;
      const int lane = khalf * 32 + (o & 31);
      const int tile = (ks * 2 + t) * 4 + (o >> 5);
      wP[tile * 512 + lane * 8 + ko] = v;
    }
  }
}

// ---------------- A[o,i] = sum_c Wa[o,c]*f[i,c] ----------------
// grid 128: 8 i-tiles x 4 kq x 4 ot
__global__ __launch_bounds__(256, 2) void gemma_kernel(
    const ushort* __restrict__ fH, const ushort* __restrict__ wA,
    float* __restrict__ Aoi) {
  __shared__ float red[4][1024];
  const int tid = threadIdx.x, lane = tid & 63, w = tid >> 6;
  const int i0 = (blockIdx.x >> 4) << 5;
  const int kq = (blockIdx.x >> 2) & 3;
  const int ot = blockIdx.x & 3;
  const int rr = lane & 31, half = lane >> 5;
  floatx16 a4;
  #pragma unroll
  for (int r = 0; r < 16; ++r) a4[r] = 0.0f;
  const int kbase = kq * 320 + w * 80 + half * 8;
  #pragma unroll
  for (int ks = 0; ks < 5; ++ks) {
    const int k = kbase + ks * 16;
    U4H8 bf; bf.u = *(const uint4*)(fH + (i0 + rr) * 1280 + k);
    U4H8 af; af.u = *(const uint4*)(wA + (ot * 32 + rr) * 1280 + k);
    a4 = __builtin_amdgcn_mfma_f32_32x32x16_f16(af.h, bf.h, a4, 0, 0, 0);
  }
  #pragma unroll
  for (int r = 0; r < 16; ++r) {
    const int orow = (r & 3) + 8 * (r >> 2) + 4 * half;
    red[w][orow * 32 + rr] = a4[r];
  }
  __syncthreads();
  for (int e = tid; e < 1024; e += 256) {
    float s = red[0][e] + red[1][e] + red[2][e] + red[3][e];
    atomicAdd(&Aoi[(ot * 32 + (e >> 5)) * 256 + i0 + (e & 31)], s);
  }
}

// build diff/had B-fragments: packed f16, no unpack/repack.
__device__ inline void build_pair(const uint4 vj, const uint4 vi, U4H8& d, U4H8& h) {
  const uint ju[4] = {vj.x, vj.y, vj.z, vj.w};
  const uint iu[4] = {vi.x, vi.y, vi.z, vi.w};
  #pragma unroll
  for (int t = 0; t < 4; ++t) {
    f16x2 a = asf16x2(iu[t]);
    f16x2 b = asf16x2(ju[t]);
    f16x2 dd = a - b;
    f16x2 hh = a * b;
    d.w[t] = asuint(dd) & 0x7fff7fffu;   // |a-b| (clear both sign bits)
    h.w[t] = asuint(hh);
  }
}

// ---------------- main fused GEMM: diff+had, K=2560, SYMMETRIC ----------
// R17: (a) x[o,i,j] == x[o,j,i] exactly (|fi-fj|, fi*fj, Aoi[i]+Aoi[j] all
// symmetric; identical f16 ops & MFMA chain order) -> compute only tiles
// with i0 < j0+64 (320 of 1024 2ix64j tiles, -37.5% work); elements whose
// mirror tile is dropped also store the mirror and count stats with wt=2.
// (b) waves are independent (no in-loop LDS/barriers) -> 640 single-wave
// blocks (64 thr), scheduler spreads 2-3 waves/CU (R8 pinned 4 on 1 CU).
// Wave = R8's: 2i x 64o x 64j, 32 MFMA/chunk, 8 acc chains, A/B reg dbuf.
__global__ __launch_bounds__(64, 2) void gemm_kernel(
    const ushort* __restrict__ fH, const ushort* __restrict__ wP,
    const float* __restrict__ bias, const float* __restrict__ Aoi,
    float* __restrict__ xout, float* __restrict__ stats) {
  const int lane = threadIdx.x;        // 64-thread block = one wave
  const int blk = blockIdx.x;          // 640 = 320 triangle tiles * 2 o-halves
  const int tp = blk >> 1;
  const int ot = blk & 1;
  int band, base;
  if (tp < 32)       { band = 0; base = 0; }
  else if (tp < 96)  { band = 1; base = 32; }
  else if (tp < 192) { band = 2; base = 96; }
  else               { band = 3; base = 192; }
  const int i0 = (tp - base) * 2;      // i-pair, i0 < j0+64 guaranteed
  const int j0 = band << 6;            // 64 j, all in-wave
  const int wo = ot << 6;
  const int rr = lane & 31;
  const int half = lane >> 5;

  const ushort* wpl = wP + ((wo >> 5) << 9) + lane * 8;
  const ushort* fi0p = fH + i0 * 1280 + half * 8;
  const ushort* fi1p = fi0p + 1280;
  const ushort* fj0p = fH + (j0 + rr) * 1280 + half * 8;
  const ushort* fj1p = fj0p + 32 * 1280;

  floatx16 acc[2][2][2];   // [i][js][oi]
  #pragma unroll
  for (int a = 0; a < 2; ++a)
    #pragma unroll
    for (int b = 0; b < 2; ++b)
      #pragma unroll
      for (int c = 0; c < 2; ++c)
        #pragma unroll
        for (int r = 0; r < 16; ++r) acc[a][b][c][r] = 0.0f;

  U4H8 wfA[8], wfB[8];
  uint4 vj0A[2], vj1A[2], vi0A[2], vi1A[2];
  uint4 vj0B[2], vj1B[2], vi0B[2], vi1B[2];

#define CHUNK_LOAD(WF, VJ0, VJ1, VI0, VI1, CC) do {                           \
    const int _b = (CC) * 16;                                                 \
    _Pragma("unroll")                                                         \
    for (int _q = 0; _q < 8; ++_q) {                                          \
      const int _st = _q >> 2, _t = (_q >> 1) & 1, _oi = _q & 1;              \
      (WF)[_q].u = *(const uint4*)(wpl + ((_b + _st * 8 + _t * 4 + _oi) << 9)); \
    }                                                                         \
    const int _cb = (CC) << 5;                                                \
    _Pragma("unroll")                                                         \
    for (int _s = 0; _s < 2; ++_s) {                                          \
      (VJ0)[_s] = *(const uint4*)(fj0p + _cb + _s * 16);                      \
      (VJ1)[_s] = *(const uint4*)(fj1p + _cb + _s * 16);                      \
      (VI0)[_s] = *(const uint4*)(fi0p + _cb + _s * 16);                      \
      (VI1)[_s] = *(const uint4*)(fi1p + _cb + _s * 16);                      \
    }                                                                         \
  } while (0)

#define CHUNK_COMPUTE(WF, VJ0, VJ1, VI0, VI1) do {                            \
    _Pragma("unroll")                                                         \
    for (int _s = 0; _s < 2; ++_s) {                                          \
      U4H8 d00, h00, d01, h01, d10, h10, d11, h11;                            \
      build_pair((VJ0)[_s], (VI0)[_s], d00, h00);                             \
      build_pair((VJ0)[_s], (VI1)[_s], d01, h01);                             \
      build_pair((VJ1)[_s], (VI0)[_s], d10, h10);                             \
      build_pair((VJ1)[_s], (VI1)[_s], d11, h11);                             \
      _Pragma("unroll")                                                       \
      for (int _oi = 0; _oi < 2; ++_oi) {                                     \
        const f16x8 wd = (WF)[_s * 4 + _oi].h;                                \
        const f16x8 wh = (WF)[_s * 4 + 2 + _oi].h;                            \
        acc[0][0][_oi] = __builtin_amdgcn_mfma_f32_32x32x16_f16(wd, d00.h, acc[0][0][_oi], 0, 0, 0); \
        acc[1][0][_oi] = __builtin_amdgcn_mfma_f32_32x32x16_f16(wd, d01.h, acc[1][0][_oi], 0, 0, 0); \
        acc[0][1][_oi] = __builtin_amdgcn_mfma_f32_32x32x16_f16(wd, d10.h, acc[0][1][_oi], 0, 0, 0); \
        acc[1][1][_oi] = __builtin_amdgcn_mfma_f32_32x32x16_f16(wd, d11.h, acc[1][1][_oi], 0, 0, 0); \
        acc[0][0][_oi] = __builtin_amdgcn_mfma_f32_32x32x16_f16(wh, h00.h, acc[0][0][_oi], 0, 0, 0); \
        acc[1][0][_oi] = __builtin_amdgcn_mfma_f32_32x32x16_f16(wh, h01.h, acc[1][0][_oi], 0, 0, 0); \
        acc[0][1][_oi] = __builtin_amdgcn_mfma_f32_32x32x16_f16(wh, h10.h, acc[0][1][_oi], 0, 0, 0); \
        acc[1][1][_oi] = __builtin_amdgcn_mfma_f32_32x32x16_f16(wh, h11.h, acc[1][1][_oi], 0, 0, 0); \
      }                                                                       \
    }                                                                         \
  } while (0)

  CHUNK_LOAD(wfA, vj0A, vj1A, vi0A, vi1A, 0);
  #pragma unroll 1
  for (int cc = 0; cc < 40; cc += 2) {
    CHUNK_LOAD(wfB, vj0B, vj1B, vi0B, vi1B, cc + 1);   // prefetch odd chunk
    CHUNK_COMPUTE(wfA, vj0A, vj1A, vi0A, vi1A);        // compute even chunk
    if (cc + 2 < 40)
      CHUNK_LOAD(wfA, vj0A, vj1A, vi0A, vi1A, cc + 2); // prefetch next even
    CHUNK_COMPUTE(wfB, vj0B, vj1B, vi0B, vi1B);        // compute odd chunk
  }
#undef CHUNK_LOAD
#undef CHUNK_COMPUTE

  // epilogue: x = acc + A[o,i] + A[o,j] + b[o]; store (+ mirror when the
  // mirror's owning tile was dropped); weighted group stats.
  float gs[2][2] = {{0.f, 0.f}, {0.f, 0.f}};   // [oi][rg]
  float gq[2][2] = {{0.f, 0.f}, {0.f, 0.f}};
  #pragma unroll
  for (int ii = 0; ii < 2; ++ii) {
    const int irow = i0 + ii;
    const int jdrop = (irow & ~63) + 64;   // mirror dropped iff (jg&~1) >= jdrop
    #pragma unroll
    for (int js = 0; js < 2; ++js) {
      const int jg = j0 + js * 32 + rr;
      const bool mdrop = (jg & ~1) >= jdrop;
      const float wt = mdrop ? 2.0f : 1.0f;
      #pragma unroll
      for (int oi = 0; oi < 2; ++oi) {
        #pragma unroll
        for (int r = 0; r < 16; ++r) {
          const int orow = (r & 3) + 8 * (r >> 2) + 4 * half;  // D row map
          const int o = wo + oi * 32 + orow;
          float x = acc[ii][js][oi][r] + Aoi[o * 256 + irow] + Aoi[o * 256 + jg] + bias[o];
          xout[o * 65536 + irow * 256 + jg] = x;
          if (mdrop) xout[o * 65536 + jg * 256 + irow] = x;   // mirror
          gs[oi][r >> 3] += wt * x;
          gq[oi][r >> 3] += wt * x * x;
        }
      }
    }
  }
  #pragma unroll
  for (int oi = 0; oi < 2; ++oi) {
    #pragma unroll
    for (int rg = 0; rg < 2; ++rg) {
      float s = gs[oi][rg], qv = gq[oi][rg];
      for (int off = 32; off > 0; off >>= 1) {
        s += __shfl_xor(s, off, 64);
        qv += __shfl_xor(qv, off, 64);
      }
      if (lane == 0) {
        const int g = (wo >> 4) + oi * 2 + rg;
        atomicAdd(&stats[g], s);
        atomicAdd(&stats[8 + g], qv);
      }
    }
  }
}

// ---------------- groupnorm + exact gelu, in place ----------------
__global__ void norm_kernel(float* __restrict__ xout,
                            const float* __restrict__ stats,
                            const float* __restrict__ gamma,
                            const float* __restrict__ beta) {
  const int idx = blockIdx.x * 256 + threadIdx.x;
  const int e = idx << 2;
  const int o = e >> 16;
  const int g = o >> 4;
  const float invN = 1.0f / 1048576.0f;  // 16*65536 per group
  const float mean = stats[g] * invN;
  const float var = stats[8 + g] * invN - mean * mean;
  const float inv = rsqrtf(var + 1e-5f);
  const float ga = gamma[o], be = beta[o];
  float4 v = *(float4*)(xout + e);
  float* pv = &v.x;
  #pragma unroll
  for (int t = 0; t < 4; ++t) {
    float xn = (pv[t] - mean) * inv * ga + be;
    pv[t] = 0.5f * xn * (1.0f + erff(xn * 0.70710678118654752f));
  }
  *(float4*)(xout + e) = v;
}

extern "C" void kernel_launch(void* const* d_in, const int* in_sizes, int n_in,
                              void* d_out, int out_size, void* d_ws, size_t ws_size,
                              hipStream_t stream) {
  const float* feats = (const float*)d_in[0];
  const float* W     = (const float*)d_in[1];
  const float* bias  = (const float*)d_in[2];
  const float* gamma = (const float*)d_in[3];
  const float* beta  = (const float*)d_in[4];
  float* out = (float*)d_out;

  ushort* fH = (ushort*)d_ws;
  ushort* wA = fH + NFEAT;
  ushort* wP = wA + NWA;
  float* stats = (float*)(wP + NWP);
  float* Aoi = stats + 16;

  prep_kernel<<<3200, 256, 0, stream>>>(feats, W, fH, wA, wP, stats, Aoi);
  gemma_kernel<<<128, 256, 0, stream>>>(fH, wA, Aoi);
  gemm_kernel<<<640, 64, 0, stream>>>(fH, wP, bias, Aoi, out, stats);
  norm_kernel<<<8192, 256, 0, stream>>>(out, stats, gamma, beta);
}

// Round 14
// 201.377 us; speedup vs baseline: 1.2801x; 1.2801x over previous
//
#include <hip/hip_runtime.h>
#include <math.h>

typedef unsigned int uint;
typedef unsigned short ushort;

typedef __attribute__((ext_vector_type(8))) _Float16 f16x8;
typedef __attribute__((ext_vector_type(2))) _Float16 f16x2;
typedef __attribute__((ext_vector_type(16))) float floatx16;

#define NFEAT 327680   // 256*1280 feats (f16)
#define NWA   163840   // W add-part, row-major [128][1280] (f16)
#define NWP   327680   // W diff/had part, fragment-packed (f16)
// ws: fH | wA | wP | stats f32[16] | Aoi f32[128*256]

union U4H8 { uint4 u; f16x8 h; uint w[4]; };

__device__ inline ushort f2h(float f) {
  _Float16 h = (_Float16)f;          // v_cvt_f16_f32, RNE
  union { _Float16 h; ushort s; } c; c.h = h; return c.s;
}
__device__ inline f16x2 asf16x2(uint u) {
  union { uint u; f16x2 h; } c; c.u = u; return c.h;
}
__device__ inline uint asuint(f16x2 h) {
  union { f16x2 h; uint u; } c; c.h = h; return c.u;
}

// ---------------- prep: fp32 -> fp16; W split: add row-major, diff/had packed
__global__ void prep_kernel(const float* __restrict__ feats,
                            const float* __restrict__ W,
                            ushort* __restrict__ fH,
                            ushort* __restrict__ wA,
                            ushort* __restrict__ wP,
                            float* __restrict__ stats,
                            float* __restrict__ Aoi) {
  int idx = blockIdx.x * 256 + threadIdx.x;   // 3200*256 = NFEAT+NWA+NWP
  if (blockIdx.x == 0 && threadIdx.x < 16) stats[threadIdx.x] = 0.0f;
  if (idx < 32768) Aoi[idx] = 0.0f;
  if (idx < NFEAT) {
    fH[idx] = f2h(feats[idx]);
  } else {
    const int e = idx - NFEAT;
    const int o = e / 3840;
    const int c = e - o * 3840;
    const ushort v = f2h(W[e]);
    if (c < 1280) {
      wA[o * 1280 + c] = v;
    } else {
      const int cp = c - 1280;
      const int t = cp / 1280;            // 0=diff, 1=had
      const int kk = cp - t * 1280;
      const int ks = kk >> 4;
      const int khalf = (kk >> 3) & 1;
      const int ko = kk & 7;
      const int lane = khalf * 32 + (o & 31);
      const int tile = (ks * 2 + t) * 4 + (o >> 5);
      wP[tile * 512 + lane * 8 + ko] = v;
    }
  }
}

// ---------------- A[o,i] = sum_c Wa[o,c]*f[i,c] ----------------
// grid 128: 8 i-tiles x 4 kq x 4 ot
__global__ __launch_bounds__(256, 2) void gemma_kernel(
    const ushort* __restrict__ fH, const ushort* __restrict__ wA,
    float* __restrict__ Aoi) {
  __shared__ float red[4][1024];
  const int tid = threadIdx.x, lane = tid & 63, w = tid >> 6;
  const int i0 = (blockIdx.x >> 4) << 5;
  const int kq = (blockIdx.x >> 2) & 3;
  const int ot = blockIdx.x & 3;
  const int rr = lane & 31, half = lane >> 5;
  floatx16 a4;
  #pragma unroll
  for (int r = 0; r < 16; ++r) a4[r] = 0.0f;
  const int kbase = kq * 320 + w * 80 + half * 8;
  #pragma unroll
  for (int ks = 0; ks < 5; ++ks) {
    const int k = kbase + ks * 16;
    U4H8 bf; bf.u = *(const uint4*)(fH + (i0 + rr) * 1280 + k);
    U4H8 af; af.u = *(const uint4*)(wA + (ot * 32 + rr) * 1280 + k);
    a4 = __builtin_amdgcn_mfma_f32_32x32x16_f16(af.h, bf.h, a4, 0, 0, 0);
  }
  #pragma unroll
  for (int r = 0; r < 16; ++r) {
    const int orow = (r & 3) + 8 * (r >> 2) + 4 * half;
    red[w][orow * 32 + rr] = a4[r];
  }
  __syncthreads();
  for (int e = tid; e < 1024; e += 256) {
    float s = red[0][e] + red[1][e] + red[2][e] + red[3][e];
    atomicAdd(&Aoi[(ot * 32 + (e >> 5)) * 256 + i0 + (e & 31)], s);
  }
}

// build diff/had B-fragments: packed f16, no unpack/repack.
__device__ inline void build_pair(const uint4 vj, const uint4 vi, U4H8& d, U4H8& h) {
  const uint ju[4] = {vj.x, vj.y, vj.z, vj.w};
  const uint iu[4] = {vi.x, vi.y, vi.z, vi.w};
  #pragma unroll
  for (int t = 0; t < 4; ++t) {
    f16x2 a = asf16x2(iu[t]);
    f16x2 b = asf16x2(ju[t]);
    f16x2 dd = a - b;
    f16x2 hh = a * b;
    d.w[t] = asuint(dd) & 0x7fff7fffu;   // |a-b| (clear both sign bits)
    h.w[t] = asuint(hh);
  }
}

// ---------------- main fused GEMM: diff+had, K=2560, SYMMETRIC ----------
// R18 = R12's triangle minus the scattered mirror stores. gemm computes
// only block-upper-triangle (bi <= bj at 64-granularity): 640 one-wave
// blocks (320 pair-tiles x 2 o-halves, 62.5% of full work). Own tile
// stored coalesced; stats weighted wt=2 when the mirror block is dropped
// (uniform per block). Mirrors are materialized by norm_kernel via LDS
// transpose (coalesced both sides). launch_bounds(64,1): VGPR cap 512.
__global__ __launch_bounds__(64, 1) void gemm_kernel(
    const ushort* __restrict__ fH, const ushort* __restrict__ wP,
    const float* __restrict__ bias, const float* __restrict__ Aoi,
    float* __restrict__ xout, float* __restrict__ stats) {
  const int lane = threadIdx.x;        // 64-thread block = one wave
  const int blk = blockIdx.x;          // 640 = 320 triangle tiles * 2 o-halves
  const int tp = blk >> 1;
  const int ot = blk & 1;
  int band, base;
  if (tp < 32)       { band = 0; base = 0; }
  else if (tp < 96)  { band = 1; base = 32; }
  else if (tp < 192) { band = 2; base = 96; }
  else               { band = 3; base = 192; }
  const int i0 = (tp - base) * 2;      // i-pair; (i0>>6) <= band guaranteed
  const int j0 = band << 6;            // 64 j, all in-wave
  const int wo = ot << 6;
  const int rr = lane & 31;
  const int half = lane >> 5;
  const float wt = (band > (i0 >> 6)) ? 2.0f : 1.0f;  // mirror block dropped?

  const ushort* wpl = wP + ((wo >> 5) << 9) + lane * 8;
  const ushort* fi0p = fH + i0 * 1280 + half * 8;
  const ushort* fi1p = fi0p + 1280;
  const ushort* fj0p = fH + (j0 + rr) * 1280 + half * 8;
  const ushort* fj1p = fj0p + 32 * 1280;

  floatx16 acc[2][2][2];   // [i][js][oi]
  #pragma unroll
  for (int a = 0; a < 2; ++a)
    #pragma unroll
    for (int b = 0; b < 2; ++b)
      #pragma unroll
      for (int c = 0; c < 2; ++c)
        #pragma unroll
        for (int r = 0; r < 16; ++r) acc[a][b][c][r] = 0.0f;

  U4H8 wfA[8], wfB[8];
  uint4 vj0A[2], vj1A[2], vi0A[2], vi1A[2];
  uint4 vj0B[2], vj1B[2], vi0B[2], vi1B[2];

#define CHUNK_LOAD(WF, VJ0, VJ1, VI0, VI1, CC) do {                           \
    const int _b = (CC) * 16;                                                 \
    _Pragma("unroll")                                                         \
    for (int _q = 0; _q < 8; ++_q) {                                          \
      const int _st = _q >> 2, _t = (_q >> 1) & 1, _oi = _q & 1;              \
      (WF)[_q].u = *(const uint4*)(wpl + ((_b + _st * 8 + _t * 4 + _oi) << 9)); \
    }                                                                         \
    const int _cb = (CC) << 5;                                                \
    _Pragma("unroll")                                                         \
    for (int _s = 0; _s < 2; ++_s) {                                          \
      (VJ0)[_s] = *(const uint4*)(fj0p + _cb + _s * 16);                      \
      (VJ1)[_s] = *(const uint4*)(fj1p + _cb + _s * 16);                      \
      (VI0)[_s] = *(const uint4*)(fi0p + _cb + _s * 16);                      \
      (VI1)[_s] = *(const uint4*)(fi1p + _cb + _s * 16);                      \
    }                                                                         \
  } while (0)

#define CHUNK_COMPUTE(WF, VJ0, VJ1, VI0, VI1) do {                            \
    _Pragma("unroll")                                                         \
    for (int _s = 0; _s < 2; ++_s) {                                          \
      U4H8 d00, h00, d01, h01, d10, h10, d11, h11;                            \
      build_pair((VJ0)[_s], (VI0)[_s], d00, h00);                             \
      build_pair((VJ0)[_s], (VI1)[_s], d01, h01);                             \
      build_pair((VJ1)[_s], (VI0)[_s], d10, h10);                             \
      build_pair((VJ1)[_s], (VI1)[_s], d11, h11);                             \
      _Pragma("unroll")                                                       \
      for (int _oi = 0; _oi < 2; ++_oi) {                                     \
        const f16x8 wd = (WF)[_s * 4 + _oi].h;                                \
        const f16x8 wh = (WF)[_s * 4 + 2 + _oi].h;                            \
        acc[0][0][_oi] = __builtin_amdgcn_mfma_f32_32x32x16_f16(wd, d00.h, acc[0][0][_oi], 0, 0, 0); \
        acc[1][0][_oi] = __builtin_amdgcn_mfma_f32_32x32x16_f16(wd, d01.h, acc[1][0][_oi], 0, 0, 0); \
        acc[0][1][_oi] = __builtin_amdgcn_mfma_f32_32x32x16_f16(wd, d10.h, acc[0][1][_oi], 0, 0, 0); \
        acc[1][1][_oi] = __builtin_amdgcn_mfma_f32_32x32x16_f16(wd, d11.h, acc[1][1][_oi], 0, 0, 0); \
        acc[0][0][_oi] = __builtin_amdgcn_mfma_f32_32x32x16_f16(wh, h00.h, acc[0][0][_oi], 0, 0, 0); \
        acc[1][0][_oi] = __builtin_amdgcn_mfma_f32_32x32x16_f16(wh, h01.h, acc[1][0][_oi], 0, 0, 0); \
        acc[0][1][_oi] = __builtin_amdgcn_mfma_f32_32x32x16_f16(wh, h10.h, acc[0][1][_oi], 0, 0, 0); \
        acc[1][1][_oi] = __builtin_amdgcn_mfma_f32_32x32x16_f16(wh, h11.h, acc[1][1][_oi], 0, 0, 0); \
      }                                                                       \
    }                                                                         \
  } while (0)

  CHUNK_LOAD(wfA, vj0A, vj1A, vi0A, vi1A, 0);
  #pragma unroll 1
  for (int cc = 0; cc < 40; cc += 2) {
    CHUNK_LOAD(wfB, vj0B, vj1B, vi0B, vi1B, cc + 1);   // prefetch odd chunk
    CHUNK_COMPUTE(wfA, vj0A, vj1A, vi0A, vi1A);        // compute even chunk
    if (cc + 2 < 40)
      CHUNK_LOAD(wfA, vj0A, vj1A, vi0A, vi1A, cc + 2); // prefetch next even
    CHUNK_COMPUTE(wfB, vj0B, vj1B, vi0B, vi1B);        // compute odd chunk
  }
#undef CHUNK_LOAD
#undef CHUNK_COMPUTE

  // epilogue: x = acc + A[o,i] + A[o,j] + b[o]; own-tile coalesced store;
  // weighted group stats (wt=2 when the mirror block is dropped).
  float gs[2][2] = {{0.f, 0.f}, {0.f, 0.f}};   // [oi][rg]
  float gq[2][2] = {{0.f, 0.f}, {0.f, 0.f}};
  #pragma unroll
  for (int ii = 0; ii < 2; ++ii) {
    const int irow = i0 + ii;
    #pragma unroll
    for (int js = 0; js < 2; ++js) {
      const int jg = j0 + js * 32 + rr;
      const int mglob = irow * 256 + jg;
      #pragma unroll
      for (int oi = 0; oi < 2; ++oi) {
        #pragma unroll
        for (int r = 0; r < 16; ++r) {
          const int orow = (r & 3) + 8 * (r >> 2) + 4 * half;  // D row map
          const int o = wo + oi * 32 + orow;
          float x = acc[ii][js][oi][r] + Aoi[o * 256 + irow] + Aoi[o * 256 + jg] + bias[o];
          xout[o * 65536 + mglob] = x;
          gs[oi][r >> 3] += x;
          gq[oi][r >> 3] += x * x;
        }
      }
    }
  }
  #pragma unroll
  for (int oi = 0; oi < 2; ++oi) {
    #pragma unroll
    for (int rg = 0; rg < 2; ++rg) {
      float s = wt * gs[oi][rg], qv = wt * gq[oi][rg];
      for (int off = 32; off > 0; off >>= 1) {
        s += __shfl_xor(s, off, 64);
        qv += __shfl_xor(qv, off, 64);
      }
      if (lane == 0) {
        const int g = (wo >> 4) + oi * 2 + rg;
        atomicAdd(&stats[g], s);
        atomicAdd(&stats[8 + g], qv);
      }
    }
  }
}

// ---------------- groupnorm + exact gelu + mirror fill ----------------
// grid 1280 = 128 o x 10 kept 64x64 blocks (bi <= bj). Each block
// normalizes its tile (linear read/write); off-diagonal blocks also write
// the transposed tile (final output is symmetric) via LDS 64x65 transpose
// -- both stores fully coalesced. No cross-block RAW hazard: blocks read
// only gemm output.
__global__ __launch_bounds__(256) void norm_kernel(
    float* __restrict__ xout, const float* __restrict__ stats,
    const float* __restrict__ gamma, const float* __restrict__ beta) {
  __shared__ float lds[64][65];
  const int blk = blockIdx.x;           // 1280
  const int o = blk / 10;
  const int t = blk - o * 10;
  const int bi = (t < 4) ? 0 : (t < 7) ? 1 : (t < 9) ? 2 : 3;
  const int bj = t - ((bi == 0) ? 0 : (bi == 1) ? 3 : (bi == 2) ? 5 : 6);
  const int tid = threadIdx.x;
  const int g = o >> 4;
  const float invN = 1.0f / 1048576.0f;  // 16*65536 per group
  const float mean = stats[g] * invN;
  const float var = stats[8 + g] * invN - mean * mean;
  const float ga = gamma[o] * rsqrtf(var + 1e-5f);
  const float be = beta[o];
  float* basep = xout + o * 65536;
  const bool mirror = (bi != bj);

  #pragma unroll
  for (int k = 0; k < 4; ++k) {
    const int f = tid + k * 256;
    const int r = f >> 4;               // row within tile
    const int c4 = (f & 15) << 2;       // col4 within tile
    float* p = basep + (64 * bi + r) * 256 + 64 * bj + c4;
    float4 v = *(float4*)p;
    float* pv = &v.x;
    #pragma unroll
    for (int e = 0; e < 4; ++e) {
      float xn = (pv[e] - mean) * ga + be;
      pv[e] = 0.5f * xn * (1.0f + erff(xn * 0.70710678118654752f));
    }
    *(float4*)p = v;
    if (mirror) {
      lds[r][c4 + 0] = v.x; lds[r][c4 + 1] = v.y;
      lds[r][c4 + 2] = v.z; lds[r][c4 + 3] = v.w;
    }
  }
  if (mirror) {
    __syncthreads();
    #pragma unroll
    for (int k = 0; k < 4; ++k) {
      const int f = tid + k * 256;
      const int r = f >> 4;
      const int c4 = (f & 15) << 2;
      float4 w;
      w.x = lds[c4 + 0][r]; w.y = lds[c4 + 1][r];
      w.z = lds[c4 + 2][r]; w.w = lds[c4 + 3][r];
      *(float4*)(basep + (64 * bj + r) * 256 + 64 * bi + c4) = w;
    }
  }
}

extern "C" void kernel_launch(void* const* d_in, const int* in_sizes, int n_in,
                              void* d_out, int out_size, void* d_ws, size_t ws_size,
                              hipStream_t stream) {
  const float* feats = (const float*)d_in[0];
  const float* W     = (const float*)d_in[1];
  const float* bias  = (const float*)d_in[2];
  const float* gamma = (const float*)d_in[3];
  const float* beta  = (const float*)d_in[4];
  float* out = (float*)d_out;

  ushort* fH = (ushort*)d_ws;
  ushort* wA = fH + NFEAT;
  ushort* wP = wA + NWA;
  float* stats = (float*)(wP + NWP);
  float* Aoi = stats + 16;

  prep_kernel<<<3200, 256, 0, stream>>>(feats, W, fH, wA, wP, stats, Aoi);
  gemma_kernel<<<128, 256, 0, stream>>>(fH, wA, Aoi);
  gemm_kernel<<<640, 64, 0, stream>>>(fH, wP, bias, Aoi, out, stats);
  norm_kernel<<<1280, 256, 0, stream>>>(out, stats, gamma, beta);
}